// Round 13
// baseline (2548.693 us; speedup 1.0000x reference)
//
#include <hip/hip_runtime.h>
#include <hip/hip_bf16.h>

#define DEVINL __device__ __forceinline__

typedef __attribute__((ext_vector_type(8))) short s8v;   // 8 x bf16 bits
typedef __attribute__((ext_vector_type(4))) float f4v;   // MFMA accum

using bf16 = __hip_bfloat16;
typedef unsigned short u16;

DEVINL u16 f2bu(float f) {
  bf16 h = __float2bfloat16(f);  // RNE
  return *reinterpret_cast<u16*>(&h);
}

DEVINL void gload16(const void* g, void* l) {
  // async global->LDS, 16B/lane; LDS dest = wave-uniform base + lane*16
  __builtin_amdgcn_global_load_lds((const __attribute__((address_space(1))) void*)g,
                                   (__attribute__((address_space(3))) void*)l, 16, 0, 0);
}

#define BAR()    __builtin_amdgcn_s_barrier()
#define VM(n)    asm volatile("s_waitcnt vmcnt(" #n ")" ::: "memory")

// ---------------- conversion kernels ----------------
__global__ void k_f32_to_bf16(const float* __restrict__ x, u16* __restrict__ y, long n4) {
  long i = (long)blockIdx.x * blockDim.x + threadIdx.x;
  if (i >= n4) return;
  float4 v = ((const float4*)x)[i];
  ushort4 o;
  o.x = f2bu(v.x); o.y = f2bu(v.y); o.z = f2bu(v.z); o.w = f2bu(v.w);
  ((ushort4*)y)[i] = o;
}

// W [rows][cols] fp32 -> Wt [cols][rows] bf16
__global__ void k_transpose_bf16(const float* __restrict__ W, u16* __restrict__ Wt,
                                 int rows, int cols) {
  __shared__ float tile[32][33];
  const int tx = threadIdx.x, ty = threadIdx.y;
  const int c0 = blockIdx.x * 32, r0 = blockIdx.y * 32;
  #pragma unroll
  for (int i = ty; i < 32; i += 8)
    tile[i][tx] = W[(long)(r0 + i) * cols + (c0 + tx)];
  __syncthreads();
  #pragma unroll
  for (int i = ty; i < 32; i += 8)
    Wt[(long)(c0 + i) * rows + (r0 + tx)] = f2bu(tile[tx][i]);
}

// ---------------- 256x256 GEMM: A-in-LDS (R7 path) + B-direct-global ---------
// LDS-byte roofline: R7 moved 256KB/K-tile through LDS (cap 62% MfmaUtil);
// removing B from LDS leaves 160KB (~625cy) vs MFMA 621cy -> cap ~100%.
// 8 waves (2M x 4N), BK=64, LDS 64KB = 2 dbuf x A[2ks][256][32].
// A: unchanged R7 staging+swizzle (slot j of row r holds chunk j^((r>>1)&3);
// 0-conflict, HW-verified). B: global->VGPR pairs, loaded 2 phases ahead
// (~1000cy > L2/L3 latency; weights are L2/L3-resident), compiler-gated by
// per-register vmcnt. Phase op order keeps stage-gloads BEFORE B-loads so
// compiler B-waits don't drain the A-stage queue early.
// Manual VM gates (A-stage FIFO, 10 vm-ops/tile audited): steady G2=G4=16
// at P2/P4 pre-BAR; tails 14/12; prologue VM(4) lands tile0+A10 A-data.
// EPI=1: C = bf16(relu(acc+bias[col]));  EPI=2: oacc[row] += sum relu(..)*w3
extern __shared__ char smem[];

template<int EPI, int NT>
__global__ __launch_bounds__(512, 2)
void k_gemm8(const u16* __restrict__ A, const u16* __restrict__ Bt,
             u16* __restrict__ C, const float* __restrict__ bias,
             const float* __restrict__ w3, float* __restrict__ oacc,
             int N, int K) {
  const int tid = threadIdx.x;
  const int w = tid >> 6, lane = tid & 63;
  // XCD-aware bijective swizzle (gridDim.x % 8 == 0: 2048 blocks)
  const int id = blockIdx.x;
  const int cpx = gridDim.x >> 3;
  const int sw = (id & 7) * cpx + (id >> 3);
  const int bn = sw & 7, bm = sw >> 3;          // N/256 == 8 for all our calls

  const int wm = (w >> 2) * 128, wn = (w & 3) * 64;

  f4v acc[8][4];
  #pragma unroll
  for (int i = 0; i < 8; ++i)
    #pragma unroll
    for (int jj = 0; jj < 4; ++jj)
      #pragma unroll
      for (int r = 0; r < 4; ++r) acc[i][jj][r] = 0.f;

  // ---- A staging bases (pre-swizzled global source, linear LDS dest) ----
  const int rowl = tid >> 2;                           // 0..127 row within chunk
  const int jsw = (tid & 3) ^ ((rowl >> 1) & 3);       // swizzled k-chunk
  const u16* gA = A + (long)(bm * 256 + rowl) * K + jsw * 8;   // running ptr
  const long cstr = (long)128 * K;                     // chunk-1 global row offset
  const uint wb = (uint)w * 1024u;                     // wave slice within 8KB chunk

  // ---- A ds_read base (swizzled; unchanged from R7) ----
  const uint swz = ((uint)((lane >> 4) ^ ((lane >> 1) & 3))) * 16u;
  const uint aoff = (uint)(wm + (lane & 15)) * 64u + swz;

  // ---- B direct-global base: frag(ni,ks): row bn*256+wn+ni*16+(lane&15),
  //      k = t*64 + ks*32 + (lane>>4)*8  (verified net chunk mapping) ----
  const u16* gBf = Bt + (long)(bn * 256 + wn + (lane & 15)) * K + ((lane >> 4) & 3) * 8;
  const long nstr = (long)16 * K;                      // ni stride (rows)

#define STAGE_A(pp, ks, rel) do { \
    const u16* g_ = gA + (rel) * 64 + (ks) * 32; \
    char* l_ = smem + (uint)(pp) * 32768u + (uint)(ks) * 16384u + wb; \
    gload16(g_, l_); gload16(g_ + cstr, l_ + 8192); } while (0)

#define RD_A(dst, pbc, ksb) do { \
    _Pragma("unroll") \
    for (int mi_ = 0; mi_ < 8; ++mi_) \
      dst[mi_] = *(const s8v*)(smem + (pbc) + (ksb) + aoff + (uint)mi_ * 1024u); } while (0)

#define LD_B(dst, koff, c0) do { \
    dst[0] = *(const s8v*)(gBf + (koff) + (c0) * nstr); \
    dst[1] = *(const s8v*)(gBf + (koff) + ((c0) + 1) * nstr); } while (0)

#define MFMA8(A_, B_, c0i, c1i) do { \
    __builtin_amdgcn_s_setprio(1); \
    _Pragma("unroll") \
    for (int mi_ = 0; mi_ < 8; ++mi_) { \
      acc[mi_][c0i] = __builtin_amdgcn_mfma_f32_16x16x32_bf16(A_[mi_], B_[0], acc[mi_][c0i], 0, 0, 0); \
      acc[mi_][c1i] = __builtin_amdgcn_mfma_f32_16x16x32_bf16(A_[mi_], B_[1], acc[mi_][c1i], 0, 0, 0); \
    } \
    __builtin_amdgcn_s_setprio(0); } while (0)

// One K-tile. P = buffer parity literal. KO1/KO2 = element offsets of (t,k1)
// and (t+1,k0) vs running gBf. S1: stage A-k1(t+1); S2: stage A-k0(t+2);
// R1: read next tile's a0; BL2: load next tile's B-k0. G2/G4: VM gates.
#define TILE(P, REL1, REL2, S1, S2, R1, BL2, KO1, KO2, G2N, G4N) do { \
    /* P1: stage A-k1(t+1); load B(t,k1,c01); MFMA(k0,c01) */ \
    if (S1) STAGE_A(1 - (P), 1, REL1); \
    LD_B(bk1a, KO1, 0); \
    MFMA8(a0, bk0a, 0, 1); \
    /* P2: load B(t,k1,c23); gate A-k1(t); read a1; MFMA(k0,c23) */ \
    LD_B(bk1b, KO1, 2); \
    VM(G2N); BAR(); \
    RD_A(a1, (P) * 32768u, 16384u); \
    MFMA8(a0, bk0b, 2, 3); \
    /* P3: stage A-k0(t+2); load B(t+1,k0,c01); MFMA(k1,c01) */ \
    if (S2) STAGE_A((P), 0, REL2); \
    if (BL2) LD_B(bk0a, KO2, 0); \
    MFMA8(a1, bk1a, 0, 1); \
    /* P4: load B(t+1,k0,c23); gate A-k0(t+1); read a0(next); MFMA(k1,c23) */ \
    if (BL2) LD_B(bk0b, KO2, 2); \
    if (R1) { VM(G4N); BAR(); RD_A(a0, (1 - (P)) * 32768u, 0u); } \
    MFMA8(a1, bk1b, 2, 3); \
  } while (0)

  s8v a0[8], a1[8], bk0a[2], bk0b[2], bk1a[2], bk1b[2];

  // ---- prologue: stage A00,A01,A10 (6 vm); load B(t0,k0) (4 vm);
  //      VM(4) -> all three A units landed (B pair stays in flight) ----
  STAGE_A(0, 0, 0); STAGE_A(0, 1, 0); STAGE_A(1, 0, 1);
  LD_B(bk0a, 0, 0); LD_B(bk0b, 0, 2);
  VM(4); BAR();
  RD_A(a0, 0u, 0u);

  // ---- main pairs (t, t+1), buffer parity compile-time ----
  #pragma unroll 1
  for (int tp = 0; tp < NT / 2 - 1; ++tp) {
    TILE(0, 1, 2, 1, 1, 1, 1, 32, 64, 16, 16);
    TILE(1, 2, 3, 1, 1, 1, 1, 96, 128, 16, 16);
    gA += 128; gBf += 128;
  }
  // ---- tail pair: t=NT-2 (no A-k0(NT) stage), t=NT-1 (no stages/loads) ----
  TILE(0, 1, 2, 1, 0, 1, 1, 32, 64, 16, 14);
  TILE(1, 2, 3, 0, 0, 0, 0, 96, 128, 12, 0);

  // ---- epilogue (C/D: col = lane&15, row = (lane>>4)*4 + reg) ----
  const int crow = bm * 256 + wm + ((lane >> 4) << 2);
  const int ccol = bn * 256 + wn + (lane & 15);
  if (EPI == 1) {
    #pragma unroll
    for (int jj = 0; jj < 4; ++jj) {
      const float bb = bias[ccol + jj * 16];
      #pragma unroll
      for (int mi = 0; mi < 8; ++mi)
        #pragma unroll
        for (int r = 0; r < 4; ++r) {
          float v = acc[mi][jj][r] + bb;
          v = v > 0.f ? v : 0.f;
          C[(long)(crow + mi * 16 + r) * N + ccol + jj * 16] = f2bu(v);
        }
    }
  } else {
    float bb[4], ww[4];
    #pragma unroll
    for (int jj = 0; jj < 4; ++jj) { bb[jj] = bias[ccol + jj * 16]; ww[jj] = w3[ccol + jj * 16]; }
    #pragma unroll
    for (int mi = 0; mi < 8; ++mi)
      #pragma unroll
      for (int r = 0; r < 4; ++r) {
        float s = 0.f;
        #pragma unroll
        for (int jj = 0; jj < 4; ++jj) {
          float v = acc[mi][jj][r] + bb[jj];
          v = v > 0.f ? v : 0.f;
          s += v * ww[jj];
        }
        s += __shfl_xor(s, 1, 64);
        s += __shfl_xor(s, 2, 64);
        s += __shfl_xor(s, 4, 64);
        s += __shfl_xor(s, 8, 64);
        if ((lane & 15) == 0) atomicAdd(&oacc[crow + mi * 16 + r], s);
      }
  }
#undef STAGE_A
#undef RD_A
#undef LD_B
#undef MFMA8
#undef TILE
}

// ---------------- segment ops ----------------
__global__ void k_detect(const int* __restrict__ seg, int n, int* __restrict__ flag) {
  if (blockIdx.x == 0 && threadIdx.x == 0) flag[0] = (seg[n - 1] == 0) ? 1 : 0;
}

__global__ void k_segsum(const float* __restrict__ oacc, const float* __restrict__ wacc,
                         const int* __restrict__ seg, const int* __restrict__ flag,
                         const float* __restrict__ ob3, const float* __restrict__ wb3,
                         float* __restrict__ osum, float* __restrict__ wsum, int n) {
  int i = blockIdx.x * blockDim.x + threadIdx.x;
  if (i >= n) return;
  int s = flag[0] ? seg[2 * i] : seg[i];
  atomicAdd(&osum[s], oacc[i] + ob3[0]);
  atomicAdd(&wsum[s], wacc[i] + wb3[0]);
}

__global__ void k_final(const float* __restrict__ oacc, const float* __restrict__ wacc,
                        const int* __restrict__ seg, const int* __restrict__ flag,
                        const float* __restrict__ ob3, const float* __restrict__ wb3,
                        const float* __restrict__ osum, const float* __restrict__ wsum,
                        float* __restrict__ out, int n) {
  int i = blockIdx.x * blockDim.x + threadIdx.x;
  if (i >= n) return;
  int s = flag[0] ? seg[2 * i] : seg[i];
  float o = oacc[i] + ob3[0];
  float ww = wacc[i] + wb3[0];
  out[i] = o - ww * (osum[s] / wsum[s]);
}

extern "C" void kernel_launch(void* const* d_in, const int* in_sizes, int n_in,
                              void* d_out, int out_size, void* d_ws, size_t ws_size,
                              hipStream_t stream) {
  constexpr int NA = 65536, D = 1024, H = 2048, M = 4096;
  const float* hidden = (const float*)d_in[0];
  const float* fW1 = (const float*)d_in[1];
  const float* fb1 = (const float*)d_in[2];
  const float* fW2 = (const float*)d_in[3];
  const float* fb2 = (const float*)d_in[4];
  const float* fW3 = (const float*)d_in[5];
  const float* fb3 = (const float*)d_in[6];
  const float* wW1 = (const float*)d_in[7];
  const float* wb1 = (const float*)d_in[8];
  const float* wW2 = (const float*)d_in[9];
  const float* wb2 = (const float*)d_in[10];
  const float* wW3 = (const float*)d_in[11];
  const float* wb3 = (const float*)d_in[12];
  const int* seg = (const int*)d_in[13];
  float* out = (float*)d_out;

  char* ws = (char*)d_ws;
  size_t off = 0;
  auto alloc = [&](size_t bytes) { char* p = ws + off; off += (bytes + 255) & ~(size_t)255; return p; };
  u16* hbf  = (u16*)alloc((size_t)NA * D * 2);
  u16* w1tf = (u16*)alloc((size_t)H * D * 2);
  u16* w1tw = (u16*)alloc((size_t)H * D * 2);
  u16* w2tf = (u16*)alloc((size_t)H * H * 2);
  u16* w2tw = (u16*)alloc((size_t)H * H * 2);
  u16* h1   = (u16*)alloc((size_t)NA * H * 2);
  float* oacc = (float*)alloc((size_t)NA * 4);
  float* wacc = (float*)alloc((size_t)NA * 4);
  float* osum = (float*)alloc((size_t)M * 4);
  float* wsum = (float*)alloc((size_t)M * 4);
  int* flag = (int*)alloc(256);

  // allow 64KB dynamic LDS (host-side attribute; capture-legal)
  hipFuncSetAttribute((const void*)k_gemm8<1, 16>, hipFuncAttributeMaxDynamicSharedMemorySize, 65536);
  hipFuncSetAttribute((const void*)k_gemm8<2, 32>, hipFuncAttributeMaxDynamicSharedMemorySize, 65536);

  // conversions
  k_f32_to_bf16<<<(int)((long)NA * D / 4 / 256), 256, 0, stream>>>(hidden, hbf, (long)NA * D / 4);
  dim3 tb(32, 8);
  k_transpose_bf16<<<dim3(H / 32, D / 32), tb, 0, stream>>>(fW1, w1tf, D, H);
  k_transpose_bf16<<<dim3(H / 32, D / 32), tb, 0, stream>>>(wW1, w1tw, D, H);
  k_transpose_bf16<<<dim3(H / 32, H / 32), tb, 0, stream>>>(fW2, w2tf, H, H);
  k_transpose_bf16<<<dim3(H / 32, H / 32), tb, 0, stream>>>(wW2, w2tw, H, H);

  hipMemsetAsync(oacc, 0, (size_t)((char*)flag - (char*)oacc), stream);
  k_detect<<<1, 64, 0, stream>>>(seg, NA, flag);

  const int nblk = (H / 256) * (NA / 256);   // 8 * 256 = 2048
  // ffn branch
  k_gemm8<1, 16><<<nblk, 512, 65536, stream>>>(hbf, w1tf, h1, fb1, nullptr, nullptr, H, D);
  k_gemm8<2, 32><<<nblk, 512, 65536, stream>>>(h1, w2tf, nullptr, fb2, fW3, oacc, H, H);
  // weight branch (reuses h1)
  k_gemm8<1, 16><<<nblk, 512, 65536, stream>>>(hbf, w1tw, h1, wb1, nullptr, nullptr, H, D);
  k_gemm8<2, 32><<<nblk, 512, 65536, stream>>>(h1, w2tw, nullptr, wb2, wW3, wacc, H, H);

  // segment ratio + final
  k_segsum<<<NA / 256, 256, 0, stream>>>(oacc, wacc, seg, flag, fb3, wb3, osum, wsum, NA);
  k_final<<<NA / 256, 256, 0, stream>>>(oacc, wacc, seg, flag, fb3, wb3, osum, wsum, out, NA);
}

// Round 14
// 1917.714 us; speedup vs baseline: 1.3290x; 1.3290x over previous
//
#include <hip/hip_runtime.h>
#include <hip/hip_bf16.h>

#define DEVINL __device__ __forceinline__

typedef __attribute__((ext_vector_type(8))) short s8v;   // 8 x bf16 bits
typedef __attribute__((ext_vector_type(4))) float f4v;   // MFMA accum

using bf16 = __hip_bfloat16;
typedef unsigned short u16;

DEVINL u16 f2bu(float f) {
  bf16 h = __float2bfloat16(f);  // RNE
  return *reinterpret_cast<u16*>(&h);
}

DEVINL void gload16(const void* g, void* l) {
  // async global->LDS, 16B/lane; LDS dest = wave-uniform base + lane*16
  __builtin_amdgcn_global_load_lds((const __attribute__((address_space(1))) void*)g,
                                   (__attribute__((address_space(3))) void*)l, 16, 0, 0);
}

#define BAR()    __builtin_amdgcn_s_barrier()
#define LGKM(n)  asm volatile("s_waitcnt lgkmcnt(" #n ")" ::: "memory")
#define VM(n)    asm volatile("s_waitcnt vmcnt(" #n ")" ::: "memory")

// ---------------- conversion kernels ----------------
__global__ void k_f32_to_bf16(const float* __restrict__ x, u16* __restrict__ y, long n4) {
  long i = (long)blockIdx.x * blockDim.x + threadIdx.x;
  if (i >= n4) return;
  float4 v = ((const float4*)x)[i];
  ushort4 o;
  o.x = f2bu(v.x); o.y = f2bu(v.y); o.z = f2bu(v.z); o.w = f2bu(v.w);
  ((ushort4*)y)[i] = o;
}

// W [rows][cols] fp32 -> Wt [cols][rows] bf16
__global__ void k_transpose_bf16(const float* __restrict__ W, u16* __restrict__ Wt,
                                 int rows, int cols) {
  __shared__ float tile[32][33];
  const int tx = threadIdx.x, ty = threadIdx.y;
  const int c0 = blockIdx.x * 32, r0 = blockIdx.y * 32;
  #pragma unroll
  for (int i = ty; i < 32; i += 8)
    tile[i][tx] = W[(long)(r0 + i) * cols + (c0 + tx)];
  __syncthreads();
  #pragma unroll
  for (int i = ty; i < 32; i += 8)
    Wt[(long)(c0 + i) * rows + (r0 + tx)] = f2bu(tile[tx][i]);
}

// ---------------- 256x256 GEMM, R7 schedule (terminal configuration) ---------
// Benched 3x: 1913 / 1921 / 1921 us total, MfmaUtil 43-45%, 0 bank conflicts.
// 8 waves (2M x 4N), BK=64, LDS 128KB = 2 dbuf x {A[2ks][256][32], B[2ks][256][32]}
// Swizzle: 16B slot j of row r holds k-chunk j ^ ((r>>1)&3) (0-conflict b128,
// HW-verified R3/R7/R10/R12: SQ_LDS_BANK_CONFLICT == 0).
// Fragment pipeline (counted LGKM), t-loop unrolled x2 so buffer parity is
// compile-time: ds_reads fold to base_reg+imm, stage addrs to runptr+imm.
// Drains (hand-audited FIFO, steady + tail): VM(6)@P2, VM(8)@P4; tail 4/0.
// Closed branches (measured): double-barrier lockstep (R5, -3pts), B-direct
// (R6/R13: single vmcnt FIFO couples B-waits to A-stage queue), 32x32 shape
// (R8/R9: swizzle model unreliable), 128-tile TLP (R11: waves/CU invariant).
// EPI=1: C = bf16(relu(acc+bias[col]));  EPI=2: oacc[row] += sum relu(..)*w3
extern __shared__ char smem[];

template<int EPI, int NT>
__global__ __launch_bounds__(512, 2)
void k_gemm8(const u16* __restrict__ A, const u16* __restrict__ Bt,
             u16* __restrict__ C, const float* __restrict__ bias,
             const float* __restrict__ w3, float* __restrict__ oacc,
             int N, int K) {
  const int tid = threadIdx.x;
  const int w = tid >> 6, lane = tid & 63;
  // XCD-aware bijective swizzle (gridDim.x % 8 == 0: 2048 blocks)
  const int id = blockIdx.x;
  const int cpx = gridDim.x >> 3;
  const int sw = (id & 7) * cpx + (id >> 3);
  const int bn = sw & 7, bm = sw >> 3;          // N/256 == 8 for all our calls

  const int wm = (w >> 2) * 128, wn = (w & 3) * 64;

  f4v acc[8][4];
  #pragma unroll
  for (int i = 0; i < 8; ++i)
    #pragma unroll
    for (int jj = 0; jj < 4; ++jj)
      #pragma unroll
      for (int r = 0; r < 4; ++r) acc[i][jj][r] = 0.f;

  // ---- staging bases (pre-swizzled global source, linear LDS dest) ----
  const int rowl = tid >> 2;                           // 0..127 row within chunk
  const int jsw = (tid & 3) ^ ((rowl >> 1) & 3);       // swizzled k-chunk
  const u16* gA = A + (long)(bm * 256 + rowl) * K + jsw * 8;   // running ptr
  const u16* gB = Bt + (long)(bn * 256 + rowl) * K + jsw * 8;  // running ptr
  const long cstr = (long)128 * K;                     // chunk-1 global row offset
  const uint wb = (uint)w * 1024u;                     // wave slice within 8KB chunk

  // ---- ds_read bases (swizzled) ----
  const uint swz = ((uint)((lane >> 4) ^ ((lane >> 1) & 3))) * 16u;
  const uint aoff = (uint)(wm + (lane & 15)) * 64u + swz;            // A region
  const uint boff = (uint)(wn + (lane & 15)) * 64u + swz + 32768u;   // B region

#define STAGE_A(pp, ks, rel) do { \
    const u16* g_ = gA + (rel) * 64 + (ks) * 32; \
    char* l_ = smem + (uint)(pp) * 65536u + (uint)(ks) * 16384u + wb; \
    gload16(g_, l_); gload16(g_ + cstr, l_ + 8192); } while (0)
#define STAGE_B(pp, ks, rel) do { \
    const u16* g_ = gB + (rel) * 64 + (ks) * 32; \
    char* l_ = smem + (uint)(pp) * 65536u + 32768u + (uint)(ks) * 16384u + wb; \
    gload16(g_, l_); gload16(g_ + cstr, l_ + 8192); } while (0)

#define RD_A(dst, pbc, ksb) do { \
    _Pragma("unroll") \
    for (int mi_ = 0; mi_ < 8; ++mi_) \
      dst[mi_] = *(const s8v*)(smem + (pbc) + (ksb) + aoff + (uint)mi_ * 1024u); } while (0)
#define RD_B(dst, pbc, ksb, c0) do { \
    dst[0] = *(const s8v*)(smem + (pbc) + (ksb) + boff + (uint)(c0) * 1024u); \
    dst[1] = *(const s8v*)(smem + (pbc) + (ksb) + boff + (uint)((c0) + 1) * 1024u); } while (0)

#define MFMA8(A_, B_, c0i, c1i) do { \
    __builtin_amdgcn_s_setprio(1); \
    _Pragma("unroll") \
    for (int mi_ = 0; mi_ < 8; ++mi_) { \
      acc[mi_][c0i] = __builtin_amdgcn_mfma_f32_16x16x32_bf16(A_[mi_], B_[0], acc[mi_][c0i], 0, 0, 0); \
      acc[mi_][c1i] = __builtin_amdgcn_mfma_f32_16x16x32_bf16(A_[mi_], B_[1], acc[mi_][c1i], 0, 0, 0); \
    } \
    __builtin_amdgcn_s_setprio(0); } while (0)

// One K-tile, R7 phase schedule. P = buffer parity (compile-time literal).
// REL1/REL2 = global tile offsets (vs running ptr) for t+1 / t+2 staging.
// S1 = stage (t+1).k1, S2 = stage (t+2).k0, R1 = issue next-tile P1 reads.
#define TILE(P, REL1, REL2, S1, S2, R1) do { \
    /* P1: MFMA(k0,c01); prefetch b23(k0) */ \
    RD_B(b23, (P) * 65536u, 0u, 2); \
    if (S1) STAGE_A(1 - (P), 1, REL1); \
    BAR(); LGKM(2); \
    MFMA8(a0, b01, 0, 1); \
    /* P2: MFMA(k0,c23); prefetch k1 frags */ \
    if (S1) { VM(6); } else { VM(0); } \
    BAR(); \
    RD_A(a1, (P) * 65536u, 16384u); RD_B(b01, (P) * 65536u, 16384u, 0); \
    if (S1) STAGE_B(1 - (P), 1, REL1); \
    LGKM(10); \
    MFMA8(a0, b23, 2, 3); \
    /* P3: MFMA(k1,c01); prefetch b23(k1) */ \
    RD_B(b23, (P) * 65536u, 16384u, 2); \
    if (S2) STAGE_A((P), 0, REL2); \
    BAR(); LGKM(2); \
    MFMA8(a1, b01, 0, 1); \
    /* P4: MFMA(k1,c23); prefetch next-tile k0 frags */ \
    if (S2) { \
      STAGE_B((P), 0, REL2); \
      VM(8); BAR(); \
      RD_A(a0, (1 - (P)) * 65536u, 0u); RD_B(b01, (1 - (P)) * 65536u, 0u, 0); \
      LGKM(10); \
    } else if (R1) { \
      VM(4); BAR(); \
      RD_A(a0, (1 - (P)) * 65536u, 0u); RD_B(b01, (1 - (P)) * 65536u, 0u, 0); \
      LGKM(10); \
    } else { \
      BAR(); LGKM(0); \
    } \
    MFMA8(a1, b23, 2, 3); \
  } while (0)

  s8v a0[8], a1[8], b01[2], b23[2];

  // ---- prologue: stage t0 fully + t1.k0; drain t0.k0; issue t0 P1 reads ----
  STAGE_A(0, 0, 0); STAGE_B(0, 0, 0); STAGE_A(0, 1, 0); STAGE_B(0, 1, 0);
  STAGE_A(1, 0, 1); STAGE_B(1, 0, 1);
  VM(8); BAR();
  RD_A(a0, 0u, 0u); RD_B(b01, 0u, 0u, 0);   // 10 reads in flight for P1

  // ---- main pairs (t, t+1), buffer parity compile-time ----
  #pragma unroll 1
  for (int tp = 0; tp < NT / 2 - 1; ++tp) {
    TILE(0, 1, 2, 1, 1, 1);
    TILE(1, 2, 3, 1, 1, 1);
    gA += 128; gB += 128;
  }
  // ---- tail pair: t = NT-2 (stage only (NT-1).k1), t = NT-1 (no stages) ----
  TILE(0, 1, 2, 1, 0, 1);
  TILE(1, 2, 3, 0, 0, 0);

  // ---- epilogue (C/D: col = lane&15, row = (lane>>4)*4 + reg) ----
  const int crow = bm * 256 + wm + ((lane >> 4) << 2);
  const int ccol = bn * 256 + wn + (lane & 15);
  if (EPI == 1) {
    #pragma unroll
    for (int jj = 0; jj < 4; ++jj) {
      const float bb = bias[ccol + jj * 16];
      #pragma unroll
      for (int mi = 0; mi < 8; ++mi)
        #pragma unroll
        for (int r = 0; r < 4; ++r) {
          float v = acc[mi][jj][r] + bb;
          v = v > 0.f ? v : 0.f;
          C[(long)(crow + mi * 16 + r) * N + ccol + jj * 16] = f2bu(v);
        }
    }
  } else {
    float bb[4], ww[4];
    #pragma unroll
    for (int jj = 0; jj < 4; ++jj) { bb[jj] = bias[ccol + jj * 16]; ww[jj] = w3[ccol + jj * 16]; }
    #pragma unroll
    for (int mi = 0; mi < 8; ++mi)
      #pragma unroll
      for (int r = 0; r < 4; ++r) {
        float s = 0.f;
        #pragma unroll
        for (int jj = 0; jj < 4; ++jj) {
          float v = acc[mi][jj][r] + bb[jj];
          v = v > 0.f ? v : 0.f;
          s += v * ww[jj];
        }
        s += __shfl_xor(s, 1, 64);
        s += __shfl_xor(s, 2, 64);
        s += __shfl_xor(s, 4, 64);
        s += __shfl_xor(s, 8, 64);
        if ((lane & 15) == 0) atomicAdd(&oacc[crow + mi * 16 + r], s);
      }
  }
#undef STAGE_A
#undef STAGE_B
#undef RD_A
#undef RD_B
#undef MFMA8
#undef TILE
}

// ---------------- segment ops ----------------
__global__ void k_detect(const int* __restrict__ seg, int n, int* __restrict__ flag) {
  if (blockIdx.x == 0 && threadIdx.x == 0) flag[0] = (seg[n - 1] == 0) ? 1 : 0;
}

__global__ void k_segsum(const float* __restrict__ oacc, const float* __restrict__ wacc,
                         const int* __restrict__ seg, const int* __restrict__ flag,
                         const float* __restrict__ ob3, const float* __restrict__ wb3,
                         float* __restrict__ osum, float* __restrict__ wsum, int n) {
  int i = blockIdx.x * blockDim.x + threadIdx.x;
  if (i >= n) return;
  int s = flag[0] ? seg[2 * i] : seg[i];
  atomicAdd(&osum[s], oacc[i] + ob3[0]);
  atomicAdd(&wsum[s], wacc[i] + wb3[0]);
}

__global__ void k_final(const float* __restrict__ oacc, const float* __restrict__ wacc,
                        const int* __restrict__ seg, const int* __restrict__ flag,
                        const float* __restrict__ ob3, const float* __restrict__ wb3,
                        const float* __restrict__ osum, const float* __restrict__ wsum,
                        float* __restrict__ out, int n) {
  int i = blockIdx.x * blockDim.x + threadIdx.x;
  if (i >= n) return;
  int s = flag[0] ? seg[2 * i] : seg[i];
  float o = oacc[i] + ob3[0];
  float ww = wacc[i] + wb3[0];
  out[i] = o - ww * (osum[s] / wsum[s]);
}

extern "C" void kernel_launch(void* const* d_in, const int* in_sizes, int n_in,
                              void* d_out, int out_size, void* d_ws, size_t ws_size,
                              hipStream_t stream) {
  constexpr int NA = 65536, D = 1024, H = 2048, M = 4096;
  const float* hidden = (const float*)d_in[0];
  const float* fW1 = (const float*)d_in[1];
  const float* fb1 = (const float*)d_in[2];
  const float* fW2 = (const float*)d_in[3];
  const float* fb2 = (const float*)d_in[4];
  const float* fW3 = (const float*)d_in[5];
  const float* fb3 = (const float*)d_in[6];
  const float* wW1 = (const float*)d_in[7];
  const float* wb1 = (const float*)d_in[8];
  const float* wW2 = (const float*)d_in[9];
  const float* wb2 = (const float*)d_in[10];
  const float* wW3 = (const float*)d_in[11];
  const float* wb3 = (const float*)d_in[12];
  const int* seg = (const int*)d_in[13];
  float* out = (float*)d_out;

  char* ws = (char*)d_ws;
  size_t off = 0;
  auto alloc = [&](size_t bytes) { char* p = ws + off; off += (bytes + 255) & ~(size_t)255; return p; };
  u16* hbf  = (u16*)alloc((size_t)NA * D * 2);
  u16* w1tf = (u16*)alloc((size_t)H * D * 2);
  u16* w1tw = (u16*)alloc((size_t)H * D * 2);
  u16* w2tf = (u16*)alloc((size_t)H * H * 2);
  u16* w2tw = (u16*)alloc((size_t)H * H * 2);
  u16* h1   = (u16*)alloc((size_t)NA * H * 2);
  float* oacc = (float*)alloc((size_t)NA * 4);
  float* wacc = (float*)alloc((size_t)NA * 4);
  float* osum = (float*)alloc((size_t)M * 4);
  float* wsum = (float*)alloc((size_t)M * 4);
  int* flag = (int*)alloc(256);

  // allow 128KB dynamic LDS (host-side attribute; capture-legal)
  hipFuncSetAttribute((const void*)k_gemm8<1, 16>, hipFuncAttributeMaxDynamicSharedMemorySize, 131072);
  hipFuncSetAttribute((const void*)k_gemm8<2, 32>, hipFuncAttributeMaxDynamicSharedMemorySize, 131072);

  // conversions
  k_f32_to_bf16<<<(int)((long)NA * D / 4 / 256), 256, 0, stream>>>(hidden, hbf, (long)NA * D / 4);
  dim3 tb(32, 8);
  k_transpose_bf16<<<dim3(H / 32, D / 32), tb, 0, stream>>>(fW1, w1tf, D, H);
  k_transpose_bf16<<<dim3(H / 32, D / 32), tb, 0, stream>>>(wW1, w1tw, D, H);
  k_transpose_bf16<<<dim3(H / 32, H / 32), tb, 0, stream>>>(fW2, w2tf, H, H);
  k_transpose_bf16<<<dim3(H / 32, H / 32), tb, 0, stream>>>(wW2, w2tw, H, H);

  hipMemsetAsync(oacc, 0, (size_t)((char*)flag - (char*)oacc), stream);
  k_detect<<<1, 64, 0, stream>>>(seg, NA, flag);

  const int nblk = (H / 256) * (NA / 256);   // 8 * 256 = 2048
  // ffn branch
  k_gemm8<1, 16><<<nblk, 512, 131072, stream>>>(hbf, w1tf, h1, fb1, nullptr, nullptr, H, D);
  k_gemm8<2, 32><<<nblk, 512, 131072, stream>>>(h1, w2tf, nullptr, fb2, fW3, oacc, H, H);
  // weight branch (reuses h1)
  k_gemm8<1, 16><<<nblk, 512, 131072, stream>>>(hbf, w1tw, h1, wb1, nullptr, nullptr, H, D);
  k_gemm8<2, 32><<<nblk, 512, 131072, stream>>>(h1, w2tw, nullptr, wb2, wW3, wacc, H, H);

  // segment ratio + final
  k_segsum<<<NA / 256, 256, 0, stream>>>(oacc, wacc, seg, flag, fb3, wb3, osum, wsum, NA);
  k_final<<<NA / 256, 256, 0, stream>>>(oacc, wacc, seg, flag, fb3, wb3, osum, wsum, out, NA);
}

// Round 15
// 1908.723 us; speedup vs baseline: 1.3353x; 1.0047x over previous
//
#include <hip/hip_runtime.h>
#include <hip/hip_bf16.h>

#define DEVINL __device__ __forceinline__

typedef __attribute__((ext_vector_type(8))) short s8v;   // 8 x bf16 bits
typedef __attribute__((ext_vector_type(4))) float f4v;   // MFMA accum

using bf16 = __hip_bfloat16;
typedef unsigned short u16;

DEVINL u16 f2bu(float f) {
  bf16 h = __float2bfloat16(f);  // RNE
  return *reinterpret_cast<u16*>(&h);
}

DEVINL void gload16(const void* g, void* l) {
  // async global->LDS, 16B/lane; LDS dest = wave-uniform base + lane*16
  __builtin_amdgcn_global_load_lds((const __attribute__((address_space(1))) void*)g,
                                   (__attribute__((address_space(3))) void*)l, 16, 0, 0);
}

#define BAR()    __builtin_amdgcn_s_barrier()
#define LGKM(n)  asm volatile("s_waitcnt lgkmcnt(" #n ")" ::: "memory")
#define VM(n)    asm volatile("s_waitcnt vmcnt(" #n ")" ::: "memory")

// ---------------- conversion kernels ----------------
__global__ void k_f32_to_bf16(const float* __restrict__ x, u16* __restrict__ y, long n4) {
  long i = (long)blockIdx.x * blockDim.x + threadIdx.x;
  if (i >= n4) return;
  float4 v = ((const float4*)x)[i];
  ushort4 o;
  o.x = f2bu(v.x); o.y = f2bu(v.y); o.z = f2bu(v.z); o.w = f2bu(v.w);
  ((ushort4*)y)[i] = o;
}

// Batched: all 4 weight transposes (fp32 [rows][cols] -> bf16 [cols][rows])
// in ONE launch. Tile ranges: [0,2048) fW1, [2048,4096) wW1 (1024x2048);
// [4096,8192) fW2, [8192,12288) wW2 (2048x2048). 32x32 tiles, 32x8 threads.
__global__ void k_transpose4(const float* __restrict__ fW1, u16* __restrict__ w1tf,
                             const float* __restrict__ wW1, u16* __restrict__ w1tw,
                             const float* __restrict__ fW2, u16* __restrict__ w2tf,
                             const float* __restrict__ wW2, u16* __restrict__ w2tw) {
  __shared__ float tile[32][33];
  const int bid = blockIdx.x;
  const float* W; u16* Wt; int rows, t;
  if (bid < 2048)      { W = fW1; Wt = w1tf; rows = 1024; t = bid; }
  else if (bid < 4096) { W = wW1; Wt = w1tw; rows = 1024; t = bid - 2048; }
  else if (bid < 8192) { W = fW2; Wt = w2tf; rows = 2048; t = bid - 4096; }
  else                 { W = wW2; Wt = w2tw; rows = 2048; t = bid - 8192; }
  const int cols = 2048;                       // all our weights have 2048 cols
  const int c0 = (t & 63) * 32, r0 = (t >> 6) * 32;
  const int tx = threadIdx.x, ty = threadIdx.y;
  #pragma unroll
  for (int i = ty; i < 32; i += 8)
    tile[i][tx] = W[(long)(r0 + i) * cols + (c0 + tx)];
  __syncthreads();
  #pragma unroll
  for (int i = ty; i < 32; i += 8)
    Wt[(long)(c0 + i) * rows + (r0 + tx)] = f2bu(tile[tx][i]);
}

// ---------------- 256x256 GEMM, R7 schedule (terminal configuration) ---------
// Benched 4x: 1913 / 1921 / 1921 / 1918 us total, MfmaUtil 43-45%, 0 conflicts.
// 8 waves (2M x 4N), BK=64, LDS 128KB = 2 dbuf x {A[2ks][256][32], B[2ks][256][32]}
// Swizzle: 16B slot j of row r holds k-chunk j ^ ((r>>1)&3) (0-conflict b128,
// HW-verified R3/R7/R10/R12/R14: SQ_LDS_BANK_CONFLICT == 0).
// Fragment pipeline (counted LGKM), t-loop unrolled x2 so buffer parity is
// compile-time: ds_reads fold to base_reg+imm, stage addrs to runptr+imm.
// Drains (hand-audited FIFO, steady + tail): VM(6)@P2, VM(8)@P4; tail 4/0.
// Closed branches (measured): double-barrier lockstep (R5, -3pts), B-direct
// (R6/R13: single vmcnt FIFO couples B-waits to A-stage queue), 32x32 shape
// (R8/R9: swizzle model unreliable), 128-tile TLP (R11: waves/CU invariant).
// EPI=1: C = bf16(relu(acc+bias[col]));  EPI=2: oacc[row] += sum relu(..)*w3
extern __shared__ char smem[];

template<int EPI, int NT>
__global__ __launch_bounds__(512, 2)
void k_gemm8(const u16* __restrict__ A, const u16* __restrict__ Bt,
             u16* __restrict__ C, const float* __restrict__ bias,
             const float* __restrict__ w3, float* __restrict__ oacc,
             int N, int K) {
  const int tid = threadIdx.x;
  const int w = tid >> 6, lane = tid & 63;
  // XCD-aware bijective swizzle (gridDim.x % 8 == 0: 2048 blocks)
  const int id = blockIdx.x;
  const int cpx = gridDim.x >> 3;
  const int sw = (id & 7) * cpx + (id >> 3);
  const int bn = sw & 7, bm = sw >> 3;          // N/256 == 8 for all our calls

  const int wm = (w >> 2) * 128, wn = (w & 3) * 64;

  f4v acc[8][4];
  #pragma unroll
  for (int i = 0; i < 8; ++i)
    #pragma unroll
    for (int jj = 0; jj < 4; ++jj)
      #pragma unroll
      for (int r = 0; r < 4; ++r) acc[i][jj][r] = 0.f;

  // ---- staging bases (pre-swizzled global source, linear LDS dest) ----
  const int rowl = tid >> 2;                           // 0..127 row within chunk
  const int jsw = (tid & 3) ^ ((rowl >> 1) & 3);       // swizzled k-chunk
  const u16* gA = A + (long)(bm * 256 + rowl) * K + jsw * 8;   // running ptr
  const u16* gB = Bt + (long)(bn * 256 + rowl) * K + jsw * 8;  // running ptr
  const long cstr = (long)128 * K;                     // chunk-1 global row offset
  const uint wb = (uint)w * 1024u;                     // wave slice within 8KB chunk

  // ---- ds_read bases (swizzled) ----
  const uint swz = ((uint)((lane >> 4) ^ ((lane >> 1) & 3))) * 16u;
  const uint aoff = (uint)(wm + (lane & 15)) * 64u + swz;            // A region
  const uint boff = (uint)(wn + (lane & 15)) * 64u + swz + 32768u;   // B region

#define STAGE_A(pp, ks, rel) do { \
    const u16* g_ = gA + (rel) * 64 + (ks) * 32; \
    char* l_ = smem + (uint)(pp) * 65536u + (uint)(ks) * 16384u + wb; \
    gload16(g_, l_); gload16(g_ + cstr, l_ + 8192); } while (0)
#define STAGE_B(pp, ks, rel) do { \
    const u16* g_ = gB + (rel) * 64 + (ks) * 32; \
    char* l_ = smem + (uint)(pp) * 65536u + 32768u + (uint)(ks) * 16384u + wb; \
    gload16(g_, l_); gload16(g_ + cstr, l_ + 8192); } while (0)

#define RD_A(dst, pbc, ksb) do { \
    _Pragma("unroll") \
    for (int mi_ = 0; mi_ < 8; ++mi_) \
      dst[mi_] = *(const s8v*)(smem + (pbc) + (ksb) + aoff + (uint)mi_ * 1024u); } while (0)
#define RD_B(dst, pbc, ksb, c0) do { \
    dst[0] = *(const s8v*)(smem + (pbc) + (ksb) + boff + (uint)(c0) * 1024u); \
    dst[1] = *(const s8v*)(smem + (pbc) + (ksb) + boff + (uint)((c0) + 1) * 1024u); } while (0)

#define MFMA8(A_, B_, c0i, c1i) do { \
    __builtin_amdgcn_s_setprio(1); \
    _Pragma("unroll") \
    for (int mi_ = 0; mi_ < 8; ++mi_) { \
      acc[mi_][c0i] = __builtin_amdgcn_mfma_f32_16x16x32_bf16(A_[mi_], B_[0], acc[mi_][c0i], 0, 0, 0); \
      acc[mi_][c1i] = __builtin_amdgcn_mfma_f32_16x16x32_bf16(A_[mi_], B_[1], acc[mi_][c1i], 0, 0, 0); \
    } \
    __builtin_amdgcn_s_setprio(0); } while (0)

// One K-tile, R7 phase schedule. P = buffer parity (compile-time literal).
// REL1/REL2 = global tile offsets (vs running ptr) for t+1 / t+2 staging.
// S1 = stage (t+1).k1, S2 = stage (t+2).k0, R1 = issue next-tile P1 reads.
#define TILE(P, REL1, REL2, S1, S2, R1) do { \
    /* P1: MFMA(k0,c01); prefetch b23(k0) */ \
    RD_B(b23, (P) * 65536u, 0u, 2); \
    if (S1) STAGE_A(1 - (P), 1, REL1); \
    BAR(); LGKM(2); \
    MFMA8(a0, b01, 0, 1); \
    /* P2: MFMA(k0,c23); prefetch k1 frags */ \
    if (S1) { VM(6); } else { VM(0); } \
    BAR(); \
    RD_A(a1, (P) * 65536u, 16384u); RD_B(b01, (P) * 65536u, 16384u, 0); \
    if (S1) STAGE_B(1 - (P), 1, REL1); \
    LGKM(10); \
    MFMA8(a0, b23, 2, 3); \
    /* P3: MFMA(k1,c01); prefetch b23(k1) */ \
    RD_B(b23, (P) * 65536u, 16384u, 2); \
    if (S2) STAGE_A((P), 0, REL2); \
    BAR(); LGKM(2); \
    MFMA8(a1, b01, 0, 1); \
    /* P4: MFMA(k1,c23); prefetch next-tile k0 frags */ \
    if (S2) { \
      STAGE_B((P), 0, REL2); \
      VM(8); BAR(); \
      RD_A(a0, (1 - (P)) * 65536u, 0u); RD_B(b01, (1 - (P)) * 65536u, 0u, 0); \
      LGKM(10); \
    } else if (R1) { \
      VM(4); BAR(); \
      RD_A(a0, (1 - (P)) * 65536u, 0u); RD_B(b01, (1 - (P)) * 65536u, 0u, 0); \
      LGKM(10); \
    } else { \
      BAR(); LGKM(0); \
    } \
    MFMA8(a1, b23, 2, 3); \
  } while (0)

  s8v a0[8], a1[8], b01[2], b23[2];

  // ---- prologue: stage t0 fully + t1.k0; drain t0.k0; issue t0 P1 reads ----
  STAGE_A(0, 0, 0); STAGE_B(0, 0, 0); STAGE_A(0, 1, 0); STAGE_B(0, 1, 0);
  STAGE_A(1, 0, 1); STAGE_B(1, 0, 1);
  VM(8); BAR();
  RD_A(a0, 0u, 0u); RD_B(b01, 0u, 0u, 0);   // 10 reads in flight for P1

  // ---- main pairs (t, t+1), buffer parity compile-time ----
  #pragma unroll 1
  for (int tp = 0; tp < NT / 2 - 1; ++tp) {
    TILE(0, 1, 2, 1, 1, 1);
    TILE(1, 2, 3, 1, 1, 1);
    gA += 128; gB += 128;
  }
  // ---- tail pair: t = NT-2 (stage only (NT-1).k1), t = NT-1 (no stages) ----
  TILE(0, 1, 2, 1, 0, 1);
  TILE(1, 2, 3, 0, 0, 0);

  // ---- epilogue (C/D: col = lane&15, row = (lane>>4)*4 + reg) ----
  const int crow = bm * 256 + wm + ((lane >> 4) << 2);
  const int ccol = bn * 256 + wn + (lane & 15);
  if (EPI == 1) {
    #pragma unroll
    for (int jj = 0; jj < 4; ++jj) {
      const float bb = bias[ccol + jj * 16];
      #pragma unroll
      for (int mi = 0; mi < 8; ++mi)
        #pragma unroll
        for (int r = 0; r < 4; ++r) {
          float v = acc[mi][jj][r] + bb;
          v = v > 0.f ? v : 0.f;
          C[(long)(crow + mi * 16 + r) * N + ccol + jj * 16] = f2bu(v);
        }
    }
  } else {
    float bb[4], ww[4];
    #pragma unroll
    for (int jj = 0; jj < 4; ++jj) { bb[jj] = bias[ccol + jj * 16]; ww[jj] = w3[ccol + jj * 16]; }
    #pragma unroll
    for (int mi = 0; mi < 8; ++mi)
      #pragma unroll
      for (int r = 0; r < 4; ++r) {
        float s = 0.f;
        #pragma unroll
        for (int jj = 0; jj < 4; ++jj) {
          float v = acc[mi][jj][r] + bb[jj];
          v = v > 0.f ? v : 0.f;
          s += v * ww[jj];
        }
        s += __shfl_xor(s, 1, 64);
        s += __shfl_xor(s, 2, 64);
        s += __shfl_xor(s, 4, 64);
        s += __shfl_xor(s, 8, 64);
        if ((lane & 15) == 0) atomicAdd(&oacc[crow + mi * 16 + r], s);
      }
  }
#undef STAGE_A
#undef STAGE_B
#undef RD_A
#undef RD_B
#undef MFMA8
#undef TILE
}

// ---------------- segment ops ----------------
__global__ void k_detect(const int* __restrict__ seg, int n, int* __restrict__ flag) {
  if (blockIdx.x == 0 && threadIdx.x == 0) flag[0] = (seg[n - 1] == 0) ? 1 : 0;
}

__global__ void k_segsum(const float* __restrict__ oacc, const float* __restrict__ wacc,
                         const int* __restrict__ seg, const int* __restrict__ flag,
                         const float* __restrict__ ob3, const float* __restrict__ wb3,
                         float* __restrict__ osum, float* __restrict__ wsum, int n) {
  int i = blockIdx.x * blockDim.x + threadIdx.x;
  if (i >= n) return;
  int s = flag[0] ? seg[2 * i] : seg[i];
  atomicAdd(&osum[s], oacc[i] + ob3[0]);
  atomicAdd(&wsum[s], wacc[i] + wb3[0]);
}

__global__ void k_final(const float* __restrict__ oacc, const float* __restrict__ wacc,
                        const int* __restrict__ seg, const int* __restrict__ flag,
                        const float* __restrict__ ob3, const float* __restrict__ wb3,
                        const float* __restrict__ osum, const float* __restrict__ wsum,
                        float* __restrict__ out, int n) {
  int i = blockIdx.x * blockDim.x + threadIdx.x;
  if (i >= n) return;
  int s = flag[0] ? seg[2 * i] : seg[i];
  float o = oacc[i] + ob3[0];
  float ww = wacc[i] + wb3[0];
  out[i] = o - ww * (osum[s] / wsum[s]);
}

extern "C" void kernel_launch(void* const* d_in, const int* in_sizes, int n_in,
                              void* d_out, int out_size, void* d_ws, size_t ws_size,
                              hipStream_t stream) {
  constexpr int NA = 65536, D = 1024, H = 2048, M = 4096;
  const float* hidden = (const float*)d_in[0];
  const float* fW1 = (const float*)d_in[1];
  const float* fb1 = (const float*)d_in[2];
  const float* fW2 = (const float*)d_in[3];
  const float* fb2 = (const float*)d_in[4];
  const float* fW3 = (const float*)d_in[5];
  const float* fb3 = (const float*)d_in[6];
  const float* wW1 = (const float*)d_in[7];
  const float* wb1 = (const float*)d_in[8];
  const float* wW2 = (const float*)d_in[9];
  const float* wb2 = (const float*)d_in[10];
  const float* wW3 = (const float*)d_in[11];
  const float* wb3 = (const float*)d_in[12];
  const int* seg = (const int*)d_in[13];
  float* out = (float*)d_out;

  char* ws = (char*)d_ws;
  size_t off = 0;
  auto alloc = [&](size_t bytes) { char* p = ws + off; off += (bytes + 255) & ~(size_t)255; return p; };
  u16* hbf  = (u16*)alloc((size_t)NA * D * 2);
  u16* w1tf = (u16*)alloc((size_t)H * D * 2);
  u16* w1tw = (u16*)alloc((size_t)H * D * 2);
  u16* w2tf = (u16*)alloc((size_t)H * H * 2);
  u16* w2tw = (u16*)alloc((size_t)H * H * 2);
  u16* h1   = (u16*)alloc((size_t)NA * H * 2);
  float* oacc = (float*)alloc((size_t)NA * 4);
  float* wacc = (float*)alloc((size_t)NA * 4);
  float* osum = (float*)alloc((size_t)M * 4);
  float* wsum = (float*)alloc((size_t)M * 4);
  int* flag = (int*)alloc(256);

  // allow 128KB dynamic LDS (host-side attribute; capture-legal)
  hipFuncSetAttribute((const void*)k_gemm8<1, 16>, hipFuncAttributeMaxDynamicSharedMemorySize, 131072);
  hipFuncSetAttribute((const void*)k_gemm8<2, 32>, hipFuncAttributeMaxDynamicSharedMemorySize, 131072);

  // conversions: hidden f32->bf16 + all 4 weight transposes in ONE launch
  k_f32_to_bf16<<<(int)((long)NA * D / 4 / 256), 256, 0, stream>>>(hidden, hbf, (long)NA * D / 4);
  k_transpose4<<<12288, dim3(32, 8), 0, stream>>>(fW1, w1tf, wW1, w1tw, fW2, w2tf, wW2, w2tw);

  hipMemsetAsync(oacc, 0, (size_t)((char*)flag - (char*)oacc), stream);
  k_detect<<<1, 64, 0, stream>>>(seg, NA, flag);

  const int nblk = (H / 256) * (NA / 256);   // 8 * 256 = 2048
  // ffn branch
  k_gemm8<1, 16><<<nblk, 512, 131072, stream>>>(hbf, w1tf, h1, fb1, nullptr, nullptr, H, D);
  k_gemm8<2, 32><<<nblk, 512, 131072, stream>>>(h1, w2tf, nullptr, fb2, fW3, oacc, H, H);
  // weight branch (reuses h1)
  k_gemm8<1, 16><<<nblk, 512, 131072, stream>>>(hbf, w1tw, h1, wb1, nullptr, nullptr, H, D);
  k_gemm8<2, 32><<<nblk, 512, 131072, stream>>>(h1, w2tw, nullptr, wb2, wW3, wacc, H, H);

  // segment ratio + final
  k_segsum<<<NA / 256, 256, 0, stream>>>(oacc, wacc, seg, flag, fb3, wb3, osum, wsum, NA);
  k_final<<<NA / 256, 256, 0, stream>>>(oacc, wacc, seg, flag, fb3, wb3, osum, wsum, out, NA);
}